// Round 2
// baseline (3001.292 us; speedup 1.0000x reference)
//
#include <hip/hip_runtime.h>
#include <math.h>

#define B_  1024
#define T_  512
#define D_  30
#define H1_ 96
#define G1_ 384
#define H2_ 64
#define G2_ 256

// Inter-kernel buffers as device globals (.bss, bound at module load).
// Fully overwritten every call before being read (no cross-call state).
__device__ float g_h1[(size_t)B_ * T_ * 192];   // 384 MiB: layer-1 output
__device__ float g_h2f[(size_t)B_ * H2_];       // layer-2 fwd final state

__device__ __forceinline__ float fast_tanh(float v) {
  float a = fabsf(v);
  float e = __expf(-2.0f * a);
  float t = 1.0f - 2.0f * e / (1.0f + e);
  return v < 0.0f ? -t : t;
}
__device__ __forceinline__ float fast_sigmoid(float v) {
  return 0.5f + 0.5f * fast_tanh(0.5f * v);   // exact identity, overflow-safe
}

#define FMAROW(a_, w_, v_)                                                    \
  a_ = fmaf(w_.x, v_.x, a_); a_ = fmaf(w_.y, v_.y, a_);                       \
  a_ = fmaf(w_.z, v_.z, a_); a_ = fmaf(w_.w, v_.w, a_);

// ---------------------------------------------------------------------------
// Layer 1: bidirectional LSTM over x (B,T,30) -> g_h1 (B,T,192)
// grid (128, 2): blockIdx.x = batch tile of 8, blockIdx.y = dir.
// 768 threads = (unit j = tid%96 owning ALL 4 gate rows j,j+96,j+192,j+288,
// k-eighth e = tid/96 -> 16 k-values). Weights still 16 named float4s; each
// broadcast LDS read of v feeds 16 FMAs -> ds_read_b128/thread/step 64->32.
// Partial sums: gbuf[row][b*8+e], stride 66 (b32 writes 2-way-free, float2
// updater reads aligned+2-way-free). Updater thread = (unit j, batch e).
// Unified input vec v[128]: [0:30)=x_t, [30:32)=0, [32:128)=h_{t-1}.
// ---------------------------------------------------------------------------
__global__ __launch_bounds__(768, 4)   // VGPR <= 128: 12-wave block always fits
void lstm1_kernel(const float* __restrict__ x,
                  const float* __restrict__ Wih_f, const float* __restrict__ Whh_f,
                  const float* __restrict__ bih_f, const float* __restrict__ bhh_f,
                  const float* __restrict__ Wih_b, const float* __restrict__ Whh_b,
                  const float* __restrict__ bih_b, const float* __restrict__ bhh_b)
{
  const int tid = threadIdx.x;
  const int dir = blockIdx.y;
  const int b0  = blockIdx.x * 8;

  const float* __restrict__ Wih = dir ? Wih_b : Wih_f;
  const float* __restrict__ Whh = dir ? Whh_b : Whh_f;
  const float* __restrict__ bih = dir ? bih_b : bih_f;
  const float* __restrict__ bhh = dir ? bhh_b : bhh_f;

  __shared__ __align__(16) float hx[8][128];     // [b][0:30 x | 32:128 h]
  __shared__ __align__(16) float gbuf[G1_ * 66]; // [row][b*8+e], ~99 KB

  const int j = tid % 96;                        // unit (gate quad), and updater unit
  const int e = tid / 96;                        // k-chunk 0..7, and updater batch

  // 16 NAMED float4 regs: 4 rows x 4 float4 over k in [16e, 16e+16).
  float4 wA0,wA1,wA2,wA3, wB0,wB1,wB2,wB3, wC0,wC1,wC2,wC3, wD0,wD1,wD2,wD3;
  if (e < 2) {                                   // k = 0..31: x-part (30 + 2 pad)
    const int k0 = e * 16;
#define LDXF(r_, kk) (((kk) < D_) ? Wih[(r_) * D_ + (kk)] : 0.0f)
#define LW4(d0,d1,d2,d3, r_) {                                                \
    d0 = make_float4(LDXF(r_,k0+ 0),LDXF(r_,k0+ 1),LDXF(r_,k0+ 2),LDXF(r_,k0+ 3)); \
    d1 = make_float4(LDXF(r_,k0+ 4),LDXF(r_,k0+ 5),LDXF(r_,k0+ 6),LDXF(r_,k0+ 7)); \
    d2 = make_float4(LDXF(r_,k0+ 8),LDXF(r_,k0+ 9),LDXF(r_,k0+10),LDXF(r_,k0+11)); \
    d3 = make_float4(LDXF(r_,k0+12),LDXF(r_,k0+13),LDXF(r_,k0+14),LDXF(r_,k0+15)); }
    LW4(wA0,wA1,wA2,wA3, j      )
    LW4(wB0,wB1,wB2,wB3, j +  96)
    LW4(wC0,wC1,wC2,wC3, j + 192)
    LW4(wD0,wD1,wD2,wD3, j + 288)
#undef LW4
#undef LDXF
  } else {                                       // k = 16e..16e+15: h-part
    const int c0 = e * 16 - 32;
    const float4* pA = (const float4*)(Whh + (j      ) * H1_ + c0);
    const float4* pB = (const float4*)(Whh + (j +  96) * H1_ + c0);
    const float4* pC = (const float4*)(Whh + (j + 192) * H1_ + c0);
    const float4* pD = (const float4*)(Whh + (j + 288) * H1_ + c0);
    wA0=pA[0]; wA1=pA[1]; wA2=pA[2]; wA3=pA[3];
    wB0=pB[0]; wB1=pB[1]; wB2=pB[2]; wB3=pB[3];
    wC0=pC[0]; wC1=pC[1]; wC2=pC[2]; wC3=pC[3];
    wD0=pD[0]; wD1=pD[1]; wD2=pD[2]; wD3=pD[3];
  }

  const float bias_i = bih[j      ] + bhh[j      ];
  const float bias_f = bih[j +  96] + bhh[j +  96];
  const float bias_g = bih[j + 192] + bhh[j + 192];
  const float bias_o = bih[j + 288] + bhh[j + 288];
  float c_state = 0.0f;

  for (int i = tid; i < 8 * 128; i += 768) (&hx[0][0])[i] = 0.0f;
  __syncthreads();
  const int xb = tid / 30;
  const int xd = tid - xb * 30;
  if (tid < 240) {
    const int t0 = dir ? (T_ - 1) : 0;
    hx[xb][xd] = x[((size_t)(b0 + xb) * T_ + t0) * D_ + xd];
  }
  __syncthreads();

  const int eoff = e * 4;                        // float4 index of k-chunk
  const float4* hx4 = (const float4*)(&hx[0][0]);
  const int rA = (j      ) * 66 + e;
  const int rB = (j +  96) * 66 + e;
  const int rC = (j + 192) * 66 + e;
  const int rD = (j + 288) * 66 + e;
  const int r2  = (j * 66 + e * 8) >> 1;         // updater float2 base (even)
  const int st2 = (96 * 66) >> 1;                // 3168: gate-row stride in float2

  for (int s = 0; s < T_; ++s) {
    const int t = dir ? (T_ - 1 - s) : s;
    float xn = 0.0f;
    if (tid < 240 && s + 1 < T_) {
      const int tn = dir ? (t - 1) : (t + 1);
      xn = x[((size_t)(b0 + xb) * T_ + tn) * D_ + xd];
    }
    float aA0=0.f,aA1=0.f,aA2=0.f,aA3=0.f,aA4=0.f,aA5=0.f,aA6=0.f,aA7=0.f;
    float aB0=0.f,aB1=0.f,aB2=0.f,aB3=0.f,aB4=0.f,aB5=0.f,aB6=0.f,aB7=0.f;
    float aC0=0.f,aC1=0.f,aC2=0.f,aC3=0.f,aC4=0.f,aC5=0.f,aC6=0.f,aC7=0.f;
    float aD0=0.f,aD1=0.f,aD2=0.f,aD3=0.f,aD4=0.f,aD5=0.f,aD6=0.f,aD7=0.f;
#define FB1(i) {                                                              \
    float4 v0 = hx4[0*32 + eoff + i]; float4 v1 = hx4[1*32 + eoff + i];       \
    float4 v2 = hx4[2*32 + eoff + i]; float4 v3 = hx4[3*32 + eoff + i];       \
    float4 v4 = hx4[4*32 + eoff + i]; float4 v5 = hx4[5*32 + eoff + i];       \
    float4 v6 = hx4[6*32 + eoff + i]; float4 v7 = hx4[7*32 + eoff + i];       \
    FMAROW(aA0, wA##i, v0) FMAROW(aB0, wB##i, v0)                             \
    FMAROW(aC0, wC##i, v0) FMAROW(aD0, wD##i, v0)                             \
    FMAROW(aA1, wA##i, v1) FMAROW(aB1, wB##i, v1)                             \
    FMAROW(aC1, wC##i, v1) FMAROW(aD1, wD##i, v1)                             \
    FMAROW(aA2, wA##i, v2) FMAROW(aB2, wB##i, v2)                             \
    FMAROW(aC2, wC##i, v2) FMAROW(aD2, wD##i, v2)                             \
    FMAROW(aA3, wA##i, v3) FMAROW(aB3, wB##i, v3)                             \
    FMAROW(aC3, wC##i, v3) FMAROW(aD3, wD##i, v3)                             \
    FMAROW(aA4, wA##i, v4) FMAROW(aB4, wB##i, v4)                             \
    FMAROW(aC4, wC##i, v4) FMAROW(aD4, wD##i, v4)                             \
    FMAROW(aA5, wA##i, v5) FMAROW(aB5, wB##i, v5)                             \
    FMAROW(aC5, wC##i, v5) FMAROW(aD5, wD##i, v5)                             \
    FMAROW(aA6, wA##i, v6) FMAROW(aB6, wB##i, v6)                             \
    FMAROW(aC6, wC##i, v6) FMAROW(aD6, wD##i, v6)                             \
    FMAROW(aA7, wA##i, v7) FMAROW(aB7, wB##i, v7)                             \
    FMAROW(aC7, wC##i, v7) FMAROW(aD7, wD##i, v7) }
    FB1(0) FB1(1) FB1(2) FB1(3)
#undef FB1
    {
      gbuf[rA+ 0]=aA0; gbuf[rA+ 8]=aA1; gbuf[rA+16]=aA2; gbuf[rA+24]=aA3;
      gbuf[rA+32]=aA4; gbuf[rA+40]=aA5; gbuf[rA+48]=aA6; gbuf[rA+56]=aA7;
      gbuf[rB+ 0]=aB0; gbuf[rB+ 8]=aB1; gbuf[rB+16]=aB2; gbuf[rB+24]=aB3;
      gbuf[rB+32]=aB4; gbuf[rB+40]=aB5; gbuf[rB+48]=aB6; gbuf[rB+56]=aB7;
      gbuf[rC+ 0]=aC0; gbuf[rC+ 8]=aC1; gbuf[rC+16]=aC2; gbuf[rC+24]=aC3;
      gbuf[rC+32]=aC4; gbuf[rC+40]=aC5; gbuf[rC+48]=aC6; gbuf[rC+56]=aC7;
      gbuf[rD+ 0]=aD0; gbuf[rD+ 8]=aD1; gbuf[rD+16]=aD2; gbuf[rD+24]=aD3;
      gbuf[rD+32]=aD4; gbuf[rD+40]=aD5; gbuf[rD+48]=aD6; gbuf[rD+56]=aD7;
    }
    __syncthreads();
    if (tid < 240 && s + 1 < T_) hx[xb][xd] = xn;
    {
      const float2* gb2 = (const float2*)gbuf;
      float2 q0,q1,q2,q3;
      q0 = gb2[r2+0]; q1 = gb2[r2+1]; q2 = gb2[r2+2]; q3 = gb2[r2+3];
      float gi = bias_i + q0.x+q0.y+q1.x+q1.y+q2.x+q2.y+q3.x+q3.y;
      q0 = gb2[r2+st2+0]; q1 = gb2[r2+st2+1]; q2 = gb2[r2+st2+2]; q3 = gb2[r2+st2+3];
      float gf = bias_f + q0.x+q0.y+q1.x+q1.y+q2.x+q2.y+q3.x+q3.y;
      q0 = gb2[r2+2*st2+0]; q1 = gb2[r2+2*st2+1]; q2 = gb2[r2+2*st2+2]; q3 = gb2[r2+2*st2+3];
      float gg = bias_g + q0.x+q0.y+q1.x+q1.y+q2.x+q2.y+q3.x+q3.y;
      q0 = gb2[r2+3*st2+0]; q1 = gb2[r2+3*st2+1]; q2 = gb2[r2+3*st2+2]; q3 = gb2[r2+3*st2+3];
      float go = bias_o + q0.x+q0.y+q1.x+q1.y+q2.x+q2.y+q3.x+q3.y;
      float iv = fast_sigmoid(gi);
      float fv = fast_sigmoid(gf);
      float ov = fast_sigmoid(go);
      c_state = fv * c_state + iv * fast_tanh(gg);
      float h = ov * fast_tanh(c_state);
      hx[e][32 + j] = h;
      g_h1[((size_t)(b0 + e) * T_ + t) * 192 + dir * 96 + j] = h;
    }
    __syncthreads();
  }
}

// ---------------------------------------------------------------------------
// Layer 2 forward scan: g_h1 (B,T,192) -> g_h2f (B,64).
// grid 256: 4 batch/block. 1024 threads = (unit j = tid&63 owning 4 gate rows
// j,j+64,j+128,j+192, k-16th e = tid>>6 -> 16 k-values). Broadcast v read
// feeds 16 FMAs -> ds_read_b128/thread/step 32->16.
// v[256]: [0:192)=h1_t, [192:256)=h2_{t-1}.
// ---------------------------------------------------------------------------
__global__ __launch_bounds__(1024, 4)
void lstm2f_kernel(const float* __restrict__ Wih, const float* __restrict__ Whh,
                   const float* __restrict__ bih, const float* __restrict__ bhh)
{
  const int tid = threadIdx.x;
  const int b0  = blockIdx.x * 4;
  const int j   = tid & 63;                      // unit (gate quad)
  const int e   = tid >> 6;                      // k-chunk 0..15 (wave-uniform)

  __shared__ __align__(16) float hx[4][256];     // [b][0:192 h1 | 192:256 h2prev]
  __shared__ __align__(16) float gbuf[G2_ * 66]; // [row][b*16+e], ~66 KB

  const int k0 = e * 16;
  float4 wA0,wA1,wA2,wA3, wB0,wB1,wB2,wB3, wC0,wC1,wC2,wC3, wD0,wD1,wD2,wD3;
  if (e < 12) {
    const float4* pA = (const float4*)(Wih + (j      ) * 192 + k0);
    const float4* pB = (const float4*)(Wih + (j +  64) * 192 + k0);
    const float4* pC = (const float4*)(Wih + (j + 128) * 192 + k0);
    const float4* pD = (const float4*)(Wih + (j + 192) * 192 + k0);
    wA0=pA[0]; wA1=pA[1]; wA2=pA[2]; wA3=pA[3];
    wB0=pB[0]; wB1=pB[1]; wB2=pB[2]; wB3=pB[3];
    wC0=pC[0]; wC1=pC[1]; wC2=pC[2]; wC3=pC[3];
    wD0=pD[0]; wD1=pD[1]; wD2=pD[2]; wD3=pD[3];
  } else {
    const int c0 = k0 - 192;
    const float4* pA = (const float4*)(Whh + (j      ) * H2_ + c0);
    const float4* pB = (const float4*)(Whh + (j +  64) * H2_ + c0);
    const float4* pC = (const float4*)(Whh + (j + 128) * H2_ + c0);
    const float4* pD = (const float4*)(Whh + (j + 192) * H2_ + c0);
    wA0=pA[0]; wA1=pA[1]; wA2=pA[2]; wA3=pA[3];
    wB0=pB[0]; wB1=pB[1]; wB2=pB[2]; wB3=pB[3];
    wC0=pC[0]; wC1=pC[1]; wC2=pC[2]; wC3=pC[3];
    wD0=pD[0]; wD1=pD[1]; wD2=pD[2]; wD3=pD[3];
  }

  const int uj = tid & 63;                       // updaters: tid < 256
  const int ub = (tid >> 6) & 3;
  const float bias_i = bih[uj      ] + bhh[uj      ];
  const float bias_f = bih[uj +  64] + bhh[uj +  64];
  const float bias_g = bih[uj + 128] + bhh[uj + 128];
  const float bias_o = bih[uj + 192] + bhh[uj + 192];
  float c_state = 0.0f;

  for (int i = tid; i < 4 * 256; i += 1024) (&hx[0][0])[i] = 0.0f;
  __syncthreads();
  const int pb = tid / 96;                       // h1 stagers: tid < 384
  const int pj = tid - pb * 96;
  if (tid < 384) {
    *(float2*)&hx[pb][pj * 2] =
        *(const float2*)&g_h1[((size_t)(b0 + pb) * T_ + 0) * 192 + pj * 2];
  }
  __syncthreads();

  const int eoff = e * 4;
  const float4* hx4 = (const float4*)(&hx[0][0]);
  const int rA = (j      ) * 66 + e;
  const int rB = (j +  64) * 66 + e;
  const int rC = (j + 128) * 66 + e;
  const int rD = (j + 192) * 66 + e;
  const int r2  = (uj * 66 + ub * 16) >> 1;      // updater float2 base (even)
  const int st2 = (64 * 66) >> 1;                // 2112

  for (int s = 0; s < T_; ++s) {
    float2 pre = make_float2(0.0f, 0.0f);
    if (tid < 384 && s + 1 < T_) {
      pre = *(const float2*)&g_h1[((size_t)(b0 + pb) * T_ + (s + 1)) * 192 + pj * 2];
    }
    float aA0=0.f,aA1=0.f,aA2=0.f,aA3=0.f;
    float aB0=0.f,aB1=0.f,aB2=0.f,aB3=0.f;
    float aC0=0.f,aC1=0.f,aC2=0.f,aC3=0.f;
    float aD0=0.f,aD1=0.f,aD2=0.f,aD3=0.f;
#define FB2(i) {                                                              \
    float4 v0 = hx4[0*64 + eoff + i]; float4 v1 = hx4[1*64 + eoff + i];       \
    float4 v2 = hx4[2*64 + eoff + i]; float4 v3 = hx4[3*64 + eoff + i];       \
    FMAROW(aA0, wA##i, v0) FMAROW(aB0, wB##i, v0)                             \
    FMAROW(aC0, wC##i, v0) FMAROW(aD0, wD##i, v0)                             \
    FMAROW(aA1, wA##i, v1) FMAROW(aB1, wB##i, v1)                             \
    FMAROW(aC1, wC##i, v1) FMAROW(aD1, wD##i, v1)                             \
    FMAROW(aA2, wA##i, v2) FMAROW(aB2, wB##i, v2)                             \
    FMAROW(aC2, wC##i, v2) FMAROW(aD2, wD##i, v2)                             \
    FMAROW(aA3, wA##i, v3) FMAROW(aB3, wB##i, v3)                             \
    FMAROW(aC3, wC##i, v3) FMAROW(aD3, wD##i, v3) }
    FB2(0) FB2(1) FB2(2) FB2(3)
#undef FB2
    {
      gbuf[rA+ 0]=aA0; gbuf[rA+16]=aA1; gbuf[rA+32]=aA2; gbuf[rA+48]=aA3;
      gbuf[rB+ 0]=aB0; gbuf[rB+16]=aB1; gbuf[rB+32]=aB2; gbuf[rB+48]=aB3;
      gbuf[rC+ 0]=aC0; gbuf[rC+16]=aC1; gbuf[rC+32]=aC2; gbuf[rC+48]=aC3;
      gbuf[rD+ 0]=aD0; gbuf[rD+16]=aD1; gbuf[rD+32]=aD2; gbuf[rD+48]=aD3;
    }
    __syncthreads();
    if (tid < 384 && s + 1 < T_) *(float2*)&hx[pb][pj * 2] = pre;
    if (tid < 256) {
      const float2* gb2 = (const float2*)gbuf;
      float gi = bias_i, gf = bias_f, gg = bias_g, go = bias_o;
#define SUM8(dst_, base_) {                                                   \
      float2 q0 = gb2[(base_)+0], q1 = gb2[(base_)+1];                        \
      float2 q2 = gb2[(base_)+2], q3 = gb2[(base_)+3];                        \
      float2 q4 = gb2[(base_)+4], q5 = gb2[(base_)+5];                        \
      float2 q6 = gb2[(base_)+6], q7 = gb2[(base_)+7];                        \
      dst_ += q0.x+q0.y+q1.x+q1.y+q2.x+q2.y+q3.x+q3.y                         \
            + q4.x+q4.y+q5.x+q5.y+q6.x+q6.y+q7.x+q7.y; }
      SUM8(gi, r2)
      SUM8(gf, r2 + st2)
      SUM8(gg, r2 + 2*st2)
      SUM8(go, r2 + 3*st2)
#undef SUM8
      float iv = fast_sigmoid(gi), fv = fast_sigmoid(gf), ov = fast_sigmoid(go);
      c_state = fv * c_state + iv * fast_tanh(gg);
      float h = ov * fast_tanh(c_state);
      hx[ub][192 + uj] = h;
      if (s == T_ - 1) g_h2f[(b0 + ub) * H2_ + uj] = h;
    }
    __syncthreads();
  }
}

// ---------------------------------------------------------------------------
// Tail: layer-2 backward (ONE step from zero state on h1[:,T-1,:]) + dense
// head. grid 128 x 256 threads, 8 batch/block. (negligible runtime)
// ---------------------------------------------------------------------------
__global__ __launch_bounds__(256)
void tail_kernel(const float* __restrict__ Wih, const float* __restrict__ bih,
                 const float* __restrict__ bhh,
                 const float* __restrict__ W1, const float* __restrict__ b1,
                 const float* __restrict__ W2, const float* __restrict__ b2,
                 float* __restrict__ out)
{
  const int tid = threadIdx.x;
  const int b0  = blockIdx.x * 8;

  __shared__ __align__(16) float hl[8][192];    // h1 at t = T-1
  __shared__ float gb[G2_ * 9];
  __shared__ __align__(16) float last[8][128];  // [h2f | h2b]
  __shared__ float db[8][32];

  for (int i = tid; i < 8 * 96; i += 256) {
    int bb = i / 96, jj = i - (i / 96) * 96;
    *(float2*)&hl[bb][jj * 2] =
        *(const float2*)&g_h1[((size_t)(b0 + bb) * T_ + (T_ - 1)) * 192 + jj * 2];
  }
  for (int i = tid; i < 8 * 64; i += 256) {
    int bb = i >> 6, jj = i & 63;
    last[bb][jj] = g_h2f[(b0 + bb) * H2_ + jj];
  }
  __syncthreads();

  {
    const int gg_ = tid;
    const float* wr = Wih + gg_ * 192;
    const float bias = bih[gg_] + bhh[gg_];
    float acc[8];
#pragma unroll
    for (int b = 0; b < 8; ++b) acc[b] = bias;
#pragma unroll 4
    for (int qq = 0; qq < 48; ++qq) {
      float4 wv = *(const float4*)&wr[qq * 4];
#pragma unroll
      for (int b = 0; b < 8; ++b) {
        float4 v = *(const float4*)&hl[b][qq * 4];
        acc[b] = fmaf(wv.x, v.x, acc[b]);
        acc[b] = fmaf(wv.y, v.y, acc[b]);
        acc[b] = fmaf(wv.z, v.z, acc[b]);
        acc[b] = fmaf(wv.w, v.w, acc[b]);
      }
    }
#pragma unroll
    for (int b = 0; b < 8; ++b) gb[gg_ * 9 + b] = acc[b];
  }
  __syncthreads();

  for (int p = tid; p < 512; p += 256) {
    int jj = p & 63, bb = p >> 6;
    float gi = gb[(jj      ) * 9 + bb];
    float gg = gb[(jj + 128) * 9 + bb];
    float go = gb[(jj + 192) * 9 + bb];
    float c  = fast_sigmoid(gi) * fast_tanh(gg);
    float h  = fast_sigmoid(go) * fast_tanh(c);
    last[bb][64 + jj] = h;
  }
  __syncthreads();

  {
    int u = tid & 31, bb = tid >> 5;
    const float* wr1 = W1 + u * 128;
    float a = b1[u];
#pragma unroll
    for (int qq = 0; qq < 32; ++qq) {
      float4 wv = *(const float4*)&wr1[qq * 4];
      float4 v  = *(const float4*)&last[bb][qq * 4];
      a = fmaf(wv.x, v.x, a); a = fmaf(wv.y, v.y, a);
      a = fmaf(wv.z, v.z, a); a = fmaf(wv.w, v.w, a);
    }
    db[bb][u] = fmaxf(a, 0.0f);
  }
  __syncthreads();

  if (tid < 8) {
    float a = b2[0];
#pragma unroll
    for (int u2 = 0; u2 < 32; ++u2) a = fmaf(db[tid][u2], W2[u2], a);
    out[b0 + tid] = a;
  }
}

extern "C" void kernel_launch(void* const* d_in, const int* in_sizes, int n_in,
                              void* d_out, int out_size, void* d_ws, size_t ws_size,
                              hipStream_t stream)
{
  const float* x     = (const float*)d_in[0];
  const float* Wih1f = (const float*)d_in[1];
  const float* Whh1f = (const float*)d_in[2];
  const float* bih1f = (const float*)d_in[3];
  const float* bhh1f = (const float*)d_in[4];
  const float* Wih1b = (const float*)d_in[5];
  const float* Whh1b = (const float*)d_in[6];
  const float* bih1b = (const float*)d_in[7];
  const float* bhh1b = (const float*)d_in[8];
  const float* Wih2f = (const float*)d_in[9];
  const float* Whh2f = (const float*)d_in[10];
  const float* bih2f = (const float*)d_in[11];
  const float* bhh2f = (const float*)d_in[12];
  const float* Wih2b = (const float*)d_in[13];
  /* Whh2b (d_in[14]) unused: layer-2 backward at t=T-1 is one step from h=0 */
  const float* bih2b = (const float*)d_in[15];
  const float* bhh2b = (const float*)d_in[16];
  const float* W1    = (const float*)d_in[17];
  const float* b1    = (const float*)d_in[18];
  const float* W2    = (const float*)d_in[19];
  const float* b2    = (const float*)d_in[20];

  (void)d_ws; (void)ws_size; (void)in_sizes; (void)n_in; (void)out_size;

  lstm1_kernel<<<dim3(128, 2), 768, 0, stream>>>(
      x, Wih1f, Whh1f, bih1f, bhh1f, Wih1b, Whh1b, bih1b, bhh1b);
  lstm2f_kernel<<<256, 1024, 0, stream>>>(
      Wih2f, Whh2f, bih2f, bhh2f);
  tail_kernel<<<128, 256, 0, stream>>>(
      Wih2b, bih2b, bhh2b, W1, b1, W2, b2, (float*)d_out);
}

// Round 3
// 2967.499 us; speedup vs baseline: 1.0114x; 1.0114x over previous
//
#include <hip/hip_runtime.h>
#include <math.h>

#define B_  1024
#define T_  512
#define D_  30
#define H1_ 96
#define G1_ 384
#define H2_ 64
#define G2_ 256

// Inter-kernel buffers as device globals (.bss, bound at module load).
// Fully overwritten every call before being read (no cross-call state).
__device__ float g_h1[(size_t)B_ * T_ * 192];   // 384 MiB: layer-1 output
__device__ float g_h2f[(size_t)B_ * H2_];       // layer-2 fwd final state

__device__ __forceinline__ float fast_tanh(float v) {
  float a = fabsf(v);
  float e = __expf(-2.0f * a);
  float t = 1.0f - 2.0f * e / (1.0f + e);
  return v < 0.0f ? -t : t;
}
__device__ __forceinline__ float fast_sigmoid(float v) {
  return 0.5f + 0.5f * fast_tanh(0.5f * v);   // exact identity, overflow-safe
}

#define FMAROW(a_, w_, v_)                                                    \
  a_ = fmaf(w_.x, v_.x, a_); a_ = fmaf(w_.y, v_.y, a_);                       \
  a_ = fmaf(w_.z, v_.z, a_); a_ = fmaf(w_.w, v_.w, a_);

// Barrier with LDS-only drain: __syncthreads() would also wait vmcnt(0),
// putting the per-step g_h1 store-ack (~200-600cy) + x prefetch on the
// critical path. LDS producer->consumer ordering only needs lgkmcnt(0).
#define BAR_LGKM() do {                                                       \
    asm volatile("s_waitcnt lgkmcnt(0)" ::: "memory");                        \
    __builtin_amdgcn_s_barrier();                                             \
    asm volatile("" ::: "memory");                                            \
  } while (0)

// ---------------------------------------------------------------------------
// Layer 1: bidirectional LSTM over x (B,T,30) -> g_h1 (B,T,192)
// grid (128, 2): blockIdx.x = batch tile of 8, blockIdx.y = dir.
// 768 threads = (unit j = tid%96 owning ALL 4 gate rows j,j+96,j+192,j+288,
// k-eighth e = tid/96 -> 16 k-values). Each broadcast LDS read of v feeds
// 16 FMAs. Partial sums: gbuf[row*67 + b*8 + e] -- stride 67 is ODD so both
// write banks (3j+const) and read banks (3j+c) are bijective mod 32 ->
// conflict-free. (R2's stride 66 hit only even banks: 1.0e8 conflict cycles.)
// Unified input vec v[128]: [0:30)=x_t, [30:32)=0, [32:128)=h_{t-1}.
// ---------------------------------------------------------------------------
__global__ __launch_bounds__(768, 4)   // VGPR <= 128: 12-wave block always fits
void lstm1_kernel(const float* __restrict__ x,
                  const float* __restrict__ Wih_f, const float* __restrict__ Whh_f,
                  const float* __restrict__ bih_f, const float* __restrict__ bhh_f,
                  const float* __restrict__ Wih_b, const float* __restrict__ Whh_b,
                  const float* __restrict__ bih_b, const float* __restrict__ bhh_b)
{
  const int tid = threadIdx.x;
  const int dir = blockIdx.y;
  const int b0  = blockIdx.x * 8;

  const float* __restrict__ Wih = dir ? Wih_b : Wih_f;
  const float* __restrict__ Whh = dir ? Whh_b : Whh_f;
  const float* __restrict__ bih = dir ? bih_b : bih_f;
  const float* __restrict__ bhh = dir ? bhh_b : bhh_f;

  __shared__ __align__(16) float hx[8][128];     // [b][0:30 x | 32:128 h]
  __shared__ float gbuf[G1_ * 67];               // [row][b*8+e], ~101 KB, odd stride

  const int j = tid % 96;                        // unit (gate quad), and updater unit
  const int e = tid / 96;                        // k-chunk 0..7, and updater batch

  // 16 NAMED float4 regs: 4 rows x 4 float4 over k in [16e, 16e+16).
  float4 wA0,wA1,wA2,wA3, wB0,wB1,wB2,wB3, wC0,wC1,wC2,wC3, wD0,wD1,wD2,wD3;
  if (e < 2) {                                   // k = 0..31: x-part (30 + 2 pad)
    const int k0 = e * 16;
#define LDXF(r_, kk) (((kk) < D_) ? Wih[(r_) * D_ + (kk)] : 0.0f)
#define LW4(d0,d1,d2,d3, r_) {                                                \
    d0 = make_float4(LDXF(r_,k0+ 0),LDXF(r_,k0+ 1),LDXF(r_,k0+ 2),LDXF(r_,k0+ 3)); \
    d1 = make_float4(LDXF(r_,k0+ 4),LDXF(r_,k0+ 5),LDXF(r_,k0+ 6),LDXF(r_,k0+ 7)); \
    d2 = make_float4(LDXF(r_,k0+ 8),LDXF(r_,k0+ 9),LDXF(r_,k0+10),LDXF(r_,k0+11)); \
    d3 = make_float4(LDXF(r_,k0+12),LDXF(r_,k0+13),LDXF(r_,k0+14),LDXF(r_,k0+15)); }
    LW4(wA0,wA1,wA2,wA3, j      )
    LW4(wB0,wB1,wB2,wB3, j +  96)
    LW4(wC0,wC1,wC2,wC3, j + 192)
    LW4(wD0,wD1,wD2,wD3, j + 288)
#undef LW4
#undef LDXF
  } else {                                       // k = 16e..16e+15: h-part
    const int c0 = e * 16 - 32;
    const float4* pA = (const float4*)(Whh + (j      ) * H1_ + c0);
    const float4* pB = (const float4*)(Whh + (j +  96) * H1_ + c0);
    const float4* pC = (const float4*)(Whh + (j + 192) * H1_ + c0);
    const float4* pD = (const float4*)(Whh + (j + 288) * H1_ + c0);
    wA0=pA[0]; wA1=pA[1]; wA2=pA[2]; wA3=pA[3];
    wB0=pB[0]; wB1=pB[1]; wB2=pB[2]; wB3=pB[3];
    wC0=pC[0]; wC1=pC[1]; wC2=pC[2]; wC3=pC[3];
    wD0=pD[0]; wD1=pD[1]; wD2=pD[2]; wD3=pD[3];
  }

  const float bias_i = bih[j      ] + bhh[j      ];
  const float bias_f = bih[j +  96] + bhh[j +  96];
  const float bias_g = bih[j + 192] + bhh[j + 192];
  const float bias_o = bih[j + 288] + bhh[j + 288];
  float c_state = 0.0f;

  for (int i = tid; i < 8 * 128; i += 768) (&hx[0][0])[i] = 0.0f;
  __syncthreads();
  const int xb = tid / 30;
  const int xd = tid - xb * 30;
  if (tid < 240) {
    const int t0 = dir ? (T_ - 1) : 0;
    hx[xb][xd] = x[((size_t)(b0 + xb) * T_ + t0) * D_ + xd];
  }
  __syncthreads();

  const int eoff = e * 4;                        // float4 index of k-chunk
  const float4* hx4 = (const float4*)(&hx[0][0]);
  const int rA = (j      ) * 67 + e;             // writer bases
  const int rB = (j +  96) * 67 + e;
  const int rC = (j + 192) * 67 + e;
  const int rD = (j + 288) * 67 + e;
  const int ur = j * 67 + e * 8;                 // updater read base (unit j, batch e)

  for (int s = 0; s < T_; ++s) {
    const int t = dir ? (T_ - 1 - s) : s;
    float xn = 0.0f;
    if (tid < 240 && s + 1 < T_) {
      const int tn = dir ? (t - 1) : (t + 1);
      xn = x[((size_t)(b0 + xb) * T_ + tn) * D_ + xd];
    }
    float aA0=0.f,aA1=0.f,aA2=0.f,aA3=0.f,aA4=0.f,aA5=0.f,aA6=0.f,aA7=0.f;
    float aB0=0.f,aB1=0.f,aB2=0.f,aB3=0.f,aB4=0.f,aB5=0.f,aB6=0.f,aB7=0.f;
    float aC0=0.f,aC1=0.f,aC2=0.f,aC3=0.f,aC4=0.f,aC5=0.f,aC6=0.f,aC7=0.f;
    float aD0=0.f,aD1=0.f,aD2=0.f,aD3=0.f,aD4=0.f,aD5=0.f,aD6=0.f,aD7=0.f;
#define FB1(i) {                                                              \
    float4 v0 = hx4[0*32 + eoff + i]; float4 v1 = hx4[1*32 + eoff + i];       \
    float4 v2 = hx4[2*32 + eoff + i]; float4 v3 = hx4[3*32 + eoff + i];       \
    float4 v4 = hx4[4*32 + eoff + i]; float4 v5 = hx4[5*32 + eoff + i];       \
    float4 v6 = hx4[6*32 + eoff + i]; float4 v7 = hx4[7*32 + eoff + i];       \
    FMAROW(aA0, wA##i, v0) FMAROW(aB0, wB##i, v0)                             \
    FMAROW(aC0, wC##i, v0) FMAROW(aD0, wD##i, v0)                             \
    FMAROW(aA1, wA##i, v1) FMAROW(aB1, wB##i, v1)                             \
    FMAROW(aC1, wC##i, v1) FMAROW(aD1, wD##i, v1)                             \
    FMAROW(aA2, wA##i, v2) FMAROW(aB2, wB##i, v2)                             \
    FMAROW(aC2, wC##i, v2) FMAROW(aD2, wD##i, v2)                             \
    FMAROW(aA3, wA##i, v3) FMAROW(aB3, wB##i, v3)                             \
    FMAROW(aC3, wC##i, v3) FMAROW(aD3, wD##i, v3)                             \
    FMAROW(aA4, wA##i, v4) FMAROW(aB4, wB##i, v4)                             \
    FMAROW(aC4, wC##i, v4) FMAROW(aD4, wD##i, v4)                             \
    FMAROW(aA5, wA##i, v5) FMAROW(aB5, wB##i, v5)                             \
    FMAROW(aC5, wC##i, v5) FMAROW(aD5, wD##i, v5)                             \
    FMAROW(aA6, wA##i, v6) FMAROW(aB6, wB##i, v6)                             \
    FMAROW(aC6, wC##i, v6) FMAROW(aD6, wD##i, v6)                             \
    FMAROW(aA7, wA##i, v7) FMAROW(aB7, wB##i, v7)                             \
    FMAROW(aC7, wC##i, v7) FMAROW(aD7, wD##i, v7) }
    FB1(0) FB1(1) FB1(2) FB1(3)
#undef FB1
    {
      gbuf[rA+ 0]=aA0; gbuf[rA+ 8]=aA1; gbuf[rA+16]=aA2; gbuf[rA+24]=aA3;
      gbuf[rA+32]=aA4; gbuf[rA+40]=aA5; gbuf[rA+48]=aA6; gbuf[rA+56]=aA7;
      gbuf[rB+ 0]=aB0; gbuf[rB+ 8]=aB1; gbuf[rB+16]=aB2; gbuf[rB+24]=aB3;
      gbuf[rB+32]=aB4; gbuf[rB+40]=aB5; gbuf[rB+48]=aB6; gbuf[rB+56]=aB7;
      gbuf[rC+ 0]=aC0; gbuf[rC+ 8]=aC1; gbuf[rC+16]=aC2; gbuf[rC+24]=aC3;
      gbuf[rC+32]=aC4; gbuf[rC+40]=aC5; gbuf[rC+48]=aC6; gbuf[rC+56]=aC7;
      gbuf[rD+ 0]=aD0; gbuf[rD+ 8]=aD1; gbuf[rD+16]=aD2; gbuf[rD+24]=aD3;
      gbuf[rD+32]=aD4; gbuf[rD+40]=aD5; gbuf[rD+48]=aD6; gbuf[rD+56]=aD7;
    }
    BAR_LGKM();
    if (tid < 240 && s + 1 < T_) hx[xb][xd] = xn;
    {
      float gi = bias_i, gf = bias_f, gg = bias_g, go = bias_o;
#pragma unroll
      for (int c = 0; c < 8; ++c) {
        gi += gbuf[ur            + c];
        gf += gbuf[ur +  96 * 67 + c];
        gg += gbuf[ur + 192 * 67 + c];
        go += gbuf[ur + 288 * 67 + c];
      }
      float iv = fast_sigmoid(gi);
      float fv = fast_sigmoid(gf);
      float ov = fast_sigmoid(go);
      c_state = fv * c_state + iv * fast_tanh(gg);
      float h = ov * fast_tanh(c_state);
      hx[e][32 + j] = h;
      g_h1[((size_t)(b0 + e) * T_ + t) * 192 + dir * 96 + j] = h;
    }
    BAR_LGKM();
  }
}

// ---------------------------------------------------------------------------
// Layer 2 forward scan: g_h1 (B,T,192) -> g_h2f (B,64).
// grid 256: 4 batch/block. 1024 threads = (unit j = tid&63 owning 4 gate rows
// j,j+64,j+128,j+192, k-16th e = tid>>6 -> 16 k-values). Broadcast v read
// feeds 16 FMAs. gbuf stride 67 (odd): conflict-free writes/reads.
// v[256]: [0:192)=h1_t, [192:256)=h2_{t-1}.
// ---------------------------------------------------------------------------
__global__ __launch_bounds__(1024, 4)
void lstm2f_kernel(const float* __restrict__ Wih, const float* __restrict__ Whh,
                   const float* __restrict__ bih, const float* __restrict__ bhh)
{
  const int tid = threadIdx.x;
  const int b0  = blockIdx.x * 4;
  const int j   = tid & 63;                      // unit (gate quad)
  const int e   = tid >> 6;                      // k-chunk 0..15 (wave-uniform)

  __shared__ __align__(16) float hx[4][256];     // [b][0:192 h1 | 192:256 h2prev]
  __shared__ float gbuf[G2_ * 67];               // [row][b*16+e], ~67 KB, odd stride

  const int k0 = e * 16;
  float4 wA0,wA1,wA2,wA3, wB0,wB1,wB2,wB3, wC0,wC1,wC2,wC3, wD0,wD1,wD2,wD3;
  if (e < 12) {
    const float4* pA = (const float4*)(Wih + (j      ) * 192 + k0);
    const float4* pB = (const float4*)(Wih + (j +  64) * 192 + k0);
    const float4* pC = (const float4*)(Wih + (j + 128) * 192 + k0);
    const float4* pD = (const float4*)(Wih + (j + 192) * 192 + k0);
    wA0=pA[0]; wA1=pA[1]; wA2=pA[2]; wA3=pA[3];
    wB0=pB[0]; wB1=pB[1]; wB2=pB[2]; wB3=pB[3];
    wC0=pC[0]; wC1=pC[1]; wC2=pC[2]; wC3=pC[3];
    wD0=pD[0]; wD1=pD[1]; wD2=pD[2]; wD3=pD[3];
  } else {
    const int c0 = k0 - 192;
    const float4* pA = (const float4*)(Whh + (j      ) * H2_ + c0);
    const float4* pB = (const float4*)(Whh + (j +  64) * H2_ + c0);
    const float4* pC = (const float4*)(Whh + (j + 128) * H2_ + c0);
    const float4* pD = (const float4*)(Whh + (j + 192) * H2_ + c0);
    wA0=pA[0]; wA1=pA[1]; wA2=pA[2]; wA3=pA[3];
    wB0=pB[0]; wB1=pB[1]; wB2=pB[2]; wB3=pB[3];
    wC0=pC[0]; wC1=pC[1]; wC2=pC[2]; wC3=pC[3];
    wD0=pD[0]; wD1=pD[1]; wD2=pD[2]; wD3=pD[3];
  }

  const int uj = tid & 63;                       // updaters: tid < 256
  const int ub = (tid >> 6) & 3;
  const float bias_i = bih[uj      ] + bhh[uj      ];
  const float bias_f = bih[uj +  64] + bhh[uj +  64];
  const float bias_g = bih[uj + 128] + bhh[uj + 128];
  const float bias_o = bih[uj + 192] + bhh[uj + 192];
  float c_state = 0.0f;

  for (int i = tid; i < 4 * 256; i += 1024) (&hx[0][0])[i] = 0.0f;
  __syncthreads();
  const int pb = tid / 96;                       // h1 stagers: tid < 384
  const int pj = tid - pb * 96;
  if (tid < 384) {
    *(float2*)&hx[pb][pj * 2] =
        *(const float2*)&g_h1[((size_t)(b0 + pb) * T_ + 0) * 192 + pj * 2];
  }
  __syncthreads();

  const int eoff = e * 4;
  const float4* hx4 = (const float4*)(&hx[0][0]);
  const int rA = (j      ) * 67 + e;             // writer bases
  const int rB = (j +  64) * 67 + e;
  const int rC = (j + 128) * 67 + e;
  const int rD = (j + 192) * 67 + e;
  const int ur = uj * 67 + ub * 16;              // updater read base

  for (int s = 0; s < T_; ++s) {
    float2 pre = make_float2(0.0f, 0.0f);
    if (tid < 384 && s + 1 < T_) {
      pre = *(const float2*)&g_h1[((size_t)(b0 + pb) * T_ + (s + 1)) * 192 + pj * 2];
    }
    float aA0=0.f,aA1=0.f,aA2=0.f,aA3=0.f;
    float aB0=0.f,aB1=0.f,aB2=0.f,aB3=0.f;
    float aC0=0.f,aC1=0.f,aC2=0.f,aC3=0.f;
    float aD0=0.f,aD1=0.f,aD2=0.f,aD3=0.f;
#define FB2(i) {                                                              \
    float4 v0 = hx4[0*64 + eoff + i]; float4 v1 = hx4[1*64 + eoff + i];       \
    float4 v2 = hx4[2*64 + eoff + i]; float4 v3 = hx4[3*64 + eoff + i];       \
    FMAROW(aA0, wA##i, v0) FMAROW(aB0, wB##i, v0)                             \
    FMAROW(aC0, wC##i, v0) FMAROW(aD0, wD##i, v0)                             \
    FMAROW(aA1, wA##i, v1) FMAROW(aB1, wB##i, v1)                             \
    FMAROW(aC1, wC##i, v1) FMAROW(aD1, wD##i, v1)                             \
    FMAROW(aA2, wA##i, v2) FMAROW(aB2, wB##i, v2)                             \
    FMAROW(aC2, wC##i, v2) FMAROW(aD2, wD##i, v2)                             \
    FMAROW(aA3, wA##i, v3) FMAROW(aB3, wB##i, v3)                             \
    FMAROW(aC3, wC##i, v3) FMAROW(aD3, wD##i, v3) }
    FB2(0) FB2(1) FB2(2) FB2(3)
#undef FB2
    {
      gbuf[rA+ 0]=aA0; gbuf[rA+16]=aA1; gbuf[rA+32]=aA2; gbuf[rA+48]=aA3;
      gbuf[rB+ 0]=aB0; gbuf[rB+16]=aB1; gbuf[rB+32]=aB2; gbuf[rB+48]=aB3;
      gbuf[rC+ 0]=aC0; gbuf[rC+16]=aC1; gbuf[rC+32]=aC2; gbuf[rC+48]=aC3;
      gbuf[rD+ 0]=aD0; gbuf[rD+16]=aD1; gbuf[rD+32]=aD2; gbuf[rD+48]=aD3;
    }
    BAR_LGKM();
    if (tid < 384 && s + 1 < T_) *(float2*)&hx[pb][pj * 2] = pre;
    if (tid < 256) {
      float gi = bias_i, gf = bias_f, gg = bias_g, go = bias_o;
#pragma unroll
      for (int c = 0; c < 16; ++c) {
        gi += gbuf[ur            + c];
        gf += gbuf[ur +  64 * 67 + c];
        gg += gbuf[ur + 128 * 67 + c];
        go += gbuf[ur + 192 * 67 + c];
      }
      float iv = fast_sigmoid(gi), fv = fast_sigmoid(gf), ov = fast_sigmoid(go);
      c_state = fv * c_state + iv * fast_tanh(gg);
      float h = ov * fast_tanh(c_state);
      hx[ub][192 + uj] = h;
      if (s == T_ - 1) g_h2f[(b0 + ub) * H2_ + uj] = h;
    }
    BAR_LGKM();
  }
}

// ---------------------------------------------------------------------------
// Tail: layer-2 backward (ONE step from zero state on h1[:,T-1,:]) + dense
// head. grid 128 x 256 threads, 8 batch/block. (negligible runtime)
// ---------------------------------------------------------------------------
__global__ __launch_bounds__(256)
void tail_kernel(const float* __restrict__ Wih, const float* __restrict__ bih,
                 const float* __restrict__ bhh,
                 const float* __restrict__ W1, const float* __restrict__ b1,
                 const float* __restrict__ W2, const float* __restrict__ b2,
                 float* __restrict__ out)
{
  const int tid = threadIdx.x;
  const int b0  = blockIdx.x * 8;

  __shared__ __align__(16) float hl[8][192];    // h1 at t = T-1
  __shared__ float gb[G2_ * 9];
  __shared__ __align__(16) float last[8][128];  // [h2f | h2b]
  __shared__ float db[8][32];

  for (int i = tid; i < 8 * 96; i += 256) {
    int bb = i / 96, jj = i - (i / 96) * 96;
    *(float2*)&hl[bb][jj * 2] =
        *(const float2*)&g_h1[((size_t)(b0 + bb) * T_ + (T_ - 1)) * 192 + jj * 2];
  }
  for (int i = tid; i < 8 * 64; i += 256) {
    int bb = i >> 6, jj = i & 63;
    last[bb][jj] = g_h2f[(b0 + bb) * H2_ + jj];
  }
  __syncthreads();

  {
    const int gg_ = tid;
    const float* wr = Wih + gg_ * 192;
    const float bias = bih[gg_] + bhh[gg_];
    float acc[8];
#pragma unroll
    for (int b = 0; b < 8; ++b) acc[b] = bias;
#pragma unroll 4
    for (int qq = 0; qq < 48; ++qq) {
      float4 wv = *(const float4*)&wr[qq * 4];
#pragma unroll
      for (int b = 0; b < 8; ++b) {
        float4 v = *(const float4*)&hl[b][qq * 4];
        acc[b] = fmaf(wv.x, v.x, acc[b]);
        acc[b] = fmaf(wv.y, v.y, acc[b]);
        acc[b] = fmaf(wv.z, v.z, acc[b]);
        acc[b] = fmaf(wv.w, v.w, acc[b]);
      }
    }
#pragma unroll
    for (int b = 0; b < 8; ++b) gb[gg_ * 9 + b] = acc[b];
  }
  __syncthreads();

  for (int p = tid; p < 512; p += 256) {
    int jj = p & 63, bb = p >> 6;
    float gi = gb[(jj      ) * 9 + bb];
    float gg = gb[(jj + 128) * 9 + bb];
    float go = gb[(jj + 192) * 9 + bb];
    float c  = fast_sigmoid(gi) * fast_tanh(gg);
    float h  = fast_sigmoid(go) * fast_tanh(c);
    last[bb][64 + jj] = h;
  }
  __syncthreads();

  {
    int u = tid & 31, bb = tid >> 5;
    const float* wr1 = W1 + u * 128;
    float a = b1[u];
#pragma unroll
    for (int qq = 0; qq < 32; ++qq) {
      float4 wv = *(const float4*)&wr1[qq * 4];
      float4 v  = *(const float4*)&last[bb][qq * 4];
      a = fmaf(wv.x, v.x, a); a = fmaf(wv.y, v.y, a);
      a = fmaf(wv.z, v.z, a); a = fmaf(wv.w, v.w, a);
    }
    db[bb][u] = fmaxf(a, 0.0f);
  }
  __syncthreads();

  if (tid < 8) {
    float a = b2[0];
#pragma unroll
    for (int u2 = 0; u2 < 32; ++u2) a = fmaf(db[tid][u2], W2[u2], a);
    out[b0 + tid] = a;
  }
}

extern "C" void kernel_launch(void* const* d_in, const int* in_sizes, int n_in,
                              void* d_out, int out_size, void* d_ws, size_t ws_size,
                              hipStream_t stream)
{
  const float* x     = (const float*)d_in[0];
  const float* Wih1f = (const float*)d_in[1];
  const float* Whh1f = (const float*)d_in[2];
  const float* bih1f = (const float*)d_in[3];
  const float* bhh1f = (const float*)d_in[4];
  const float* Wih1b = (const float*)d_in[5];
  const float* Whh1b = (const float*)d_in[6];
  const float* bih1b = (const float*)d_in[7];
  const float* bhh1b = (const float*)d_in[8];
  const float* Wih2f = (const float*)d_in[9];
  const float* Whh2f = (const float*)d_in[10];
  const float* bih2f = (const float*)d_in[11];
  const float* bhh2f = (const float*)d_in[12];
  const float* Wih2b = (const float*)d_in[13];
  /* Whh2b (d_in[14]) unused: layer-2 backward at t=T-1 is one step from h=0 */
  const float* bih2b = (const float*)d_in[15];
  const float* bhh2b = (const float*)d_in[16];
  const float* W1    = (const float*)d_in[17];
  const float* b1    = (const float*)d_in[18];
  const float* W2    = (const float*)d_in[19];
  const float* b2    = (const float*)d_in[20];

  (void)d_ws; (void)ws_size; (void)in_sizes; (void)n_in; (void)out_size;

  lstm1_kernel<<<dim3(128, 2), 768, 0, stream>>>(
      x, Wih1f, Whh1f, bih1f, bhh1f, Wih1b, Whh1b, bih1b, bhh1b);
  lstm2f_kernel<<<256, 1024, 0, stream>>>(
      Wih2f, Whh2f, bih2f, bhh2f);
  tail_kernel<<<128, 256, 0, stream>>>(
      Wih2b, bih2b, bhh2b, W1, b1, W2, b2, (float*)d_out);
}